// Round 1
// baseline (105.609 us; speedup 1.0000x reference)
//
#include <hip/hip_runtime.h>

// Problem constants (reference: B=32, L=64, C=4)
#define BB 32
#define LL 64
#define LC 256
#define NPAIR 2016
#define WSTRIDE 2048   // ws2[b][t] padded stride (floats)

// One block per pair t=(u,v), u<v. 256 threads = 32 b * 8 k.
// Codes recomputed from L1-resident x in registers (no cross-kernel control
// data, no LDS, no barrier).
// Theta3 gather, v2: coalesced float4 row loads + in-register class select.
//   lane k of b reads row4[8m+k] (16B) -> 8 lanes cover 128B contiguous per
//   b, 1KB per wave-instruction, vs v1's ~20 partially-used lines of
//   scattered scalar dwords. Loads are UNPREDICATED (address always within
//   the 1KB row, w<=63) -- the w>v mask is a free cndmask at accumulate, so
//   all 8 loads pipeline with no divergence.
__global__ __launch_bounds__(256) void pair_kernel(
    const float* __restrict__ x, const float* __restrict__ t2,
    const float* __restrict__ t3, float* __restrict__ ws2)
{
    const int t = blockIdx.x;
    // decode triangular index t = v*(v-1)/2 + u, 0 <= u < v < 64
    int v = (int)((1.0f + sqrtf(8.0f * (float)t + 1.0f)) * 0.5f);
    while (v * (v - 1) / 2 > t) --v;
    while ((v + 1) * v / 2 <= t) ++v;
    const int u = t - v * (v - 1) / 2;

    const int tid = threadIdx.x;
    const int b = tid >> 3, k = tid & 7;
    const float4* __restrict__ x4 = (const float4*)x + b * 64;

    float4 fu = x4[u], fv = x4[v];     // prefetch (L1 broadcast)

    // argmax of u,v first: t3 row address depends ONLY on these two ->
    // shortest critical path to issuing the 8 gather loads.
    int cu = 0; { float bst = fu.x;
        if (fu.y > bst) { bst = fu.y; cu = 1; }
        if (fu.z > bst) { bst = fu.z; cu = 2; }
        if (fu.w > bst) { bst = fu.w; cu = 3; } }
    int cv = 0; { float bst = fv.x;
        if (fv.y > bst) { bst = fv.y; cv = 1; }
        if (fv.z > bst) { bst = fv.z; cv = 2; }
        if (fv.w > bst) { bst = fv.w; cv = 3; } }
    const int pu = 4 * u + cu, pv = 4 * v + cv;

    const float4* __restrict__ row4 =
        (const float4*)(t3 + ((size_t)pu << 16) + ((size_t)pv << 8));
    const float t2v = t2[pu * LC + pv];   // issue early; consumed at store

    // codes for my 8 w's (w = 8m + k), computed in registers
    int c[8];
#pragma unroll
    for (int m = 0; m < 8; ++m) {
        float4 f = x4[8 * m + k];
        int ci = 0; float best = f.x;
        if (f.y > best) { best = f.y; ci = 1; }
        if (f.z > best) { best = f.z; ci = 2; }
        if (f.w > best) { best = f.w; ci = 3; }
        c[m] = ci;
    }

    float acc = 0.0f;
#pragma unroll
    for (int m = 0; m < 8; ++m) {
        const int w = 8 * m + k;
        float4 f = row4[w];                 // coalesced 16B, always in-bounds
        const int ci = c[m];
        float lo = (ci & 1) ? f.y : f.x;    // cndmask chain, no scratch
        float hi = (ci & 1) ? f.w : f.z;
        float val = (ci & 2) ? hi : lo;
        acc += (w > v) ? val : 0.0f;        // strict-triangle mask, free
    }

    // width-8 shuffle reduce over k
    acc += __shfl_down(acc, 4, 8);
    acc += __shfl_down(acc, 2, 8);
    acc += __shfl_down(acc, 1, 8);
    if (k == 0) ws2[b * WSTRIDE + t] = acc + t2v;
}

// One block per b: sum 2016 partials (coalesced) + theta1 (argmax recomputed
// from x) + theta0.
__global__ __launch_bounds__(256) void reduce_kernel(
    const float* __restrict__ x, const float* __restrict__ t0,
    const float* __restrict__ t1, const float* __restrict__ ws2,
    float* __restrict__ out)
{
    const int b = blockIdx.x;
    const int tid = threadIdx.x;
    const float* __restrict__ wsb = ws2 + b * WSTRIDE;
    float v = 0.0f;
    for (int t = tid; t < NPAIR; t += 256) v += wsb[t];  // coalesced
    if (tid < LL) {
        float4 f = ((const float4*)x)[b * 64 + tid];
        int c = 0; float best = f.x;
        if (f.y > best) { best = f.y; c = 1; }
        if (f.z > best) { best = f.z; c = 2; }
        if (f.w > best) { best = f.w; c = 3; }
        v += t1[4 * tid + c];
    }
    for (int off = 32; off > 0; off >>= 1) v += __shfl_down(v, off, 64);
    __shared__ float wsum[4];
    if ((tid & 63) == 0) wsum[tid >> 6] = v;
    __syncthreads();
    if (tid == 0) out[b] = wsum[0] + wsum[1] + wsum[2] + wsum[3] + t0[0];
}

extern "C" void kernel_launch(void* const* d_in, const int* in_sizes, int n_in,
                              void* d_out, int out_size, void* d_ws, size_t ws_size,
                              hipStream_t stream) {
    const float* x  = (const float*)d_in[0];  // (B, L*C)
    const float* t0 = (const float*)d_in[1];  // (1,)
    const float* t1 = (const float*)d_in[2];  // (L, C)
    const float* t2 = (const float*)d_in[3];  // (L, C, L, C)
    const float* t3 = (const float*)d_in[4];  // (L, C, L, C, L, C)
    float* out = (float*)d_out;               // (B, 1)
    float* ws2 = (float*)d_ws;                // 32*2048 floats = 256 KB

    pair_kernel<<<NPAIR, 256, 0, stream>>>(x, t2, t3, ws2);
    reduce_kernel<<<BB, 256, 0, stream>>>(x, t0, t1, ws2, out);
}